// Round 2
// baseline (1040.898 us; speedup 1.0000x reference)
//
#include <hip/hip_runtime.h>

// Problem dims (fixed by reference setup_inputs)
#define NB 128
#define NT 2000
#define NN 512
#define NK 8      // t-chunks for passC
#define TC 250    // NT / NK

static __device__ __forceinline__ double d_alpha() { return 1.0 - 0.05 / 10.0; }

// ---------------------------------------------------------------------------
// passA: s64t[t*NB+b] = dot(x[b,t,:], w) in f64.  One wave per row, 4 rows/block.
// Transposed output so passB reads coalesced.
// ---------------------------------------------------------------------------
__global__ __launch_bounds__(256) void passA_dot(const float* __restrict__ x,
                                                 const float* __restrict__ w,
                                                 double* __restrict__ s64t) {
    const int wave = threadIdx.x >> 6;
    const int lane = threadIdx.x & 63;
    const long row = (long)blockIdx.x * 4 + wave;   // row = b*NT + t
    const float* xr = x + row * NN;
    const float4 a0 = *(const float4*)(xr + lane * 4);
    const float4 a1 = *(const float4*)(xr + 256 + lane * 4);
    const float4 w0 = *(const float4*)(w + lane * 4);
    const float4 w1 = *(const float4*)(w + 256 + lane * 4);
    double acc = 0.0;
    acc = fma((double)a0.x, (double)w0.x, acc);
    acc = fma((double)a0.y, (double)w0.y, acc);
    acc = fma((double)a0.z, (double)w0.z, acc);
    acc = fma((double)a0.w, (double)w0.w, acc);
    acc = fma((double)a1.x, (double)w1.x, acc);
    acc = fma((double)a1.y, (double)w1.y, acc);
    acc = fma((double)a1.z, (double)w1.z, acc);
    acc = fma((double)a1.w, (double)w1.w, acc);
#pragma unroll
    for (int off = 32; off >= 1; off >>= 1)
        acc += __shfl_xor(acc, off, 64);
    if (lane == 0) {
        const int b = (int)(row / NT);
        const int t = (int)(row - (long)b * NT);
        s64t[(long)t * NB + b] = acc;
    }
}

// ---------------------------------------------------------------------------
// passB: per-b forward scan (v, z, c, sum v^2) then backward scan (d -> e).
// 1 block, 128 threads (thread = b).  All scratch in [t][b] layout => every
// load/store in the serial loops is fully coalesced (1KB/iter).
// f64 recurrence for numpy-f64 match of the thresholded z output.
// ---------------------------------------------------------------------------
__global__ __launch_bounds__(128) void passB_scan(const double* __restrict__ s64t,
                                                  const float* __restrict__ w,
                                                  float* __restrict__ v_scr,
                                                  float* __restrict__ z_scr,
                                                  float* __restrict__ c_scr,
                                                  float* __restrict__ e_scr,
                                                  float* __restrict__ S_scr) {
    __shared__ double red[128];
    const int b = threadIdx.x;
    // ww = sum(w^2) in f64
    double wa = 0.0;
    for (int i = b; i < NN; i += 128) { const double wv = (double)w[i]; wa = fma(wv, wv, wa); }
    red[b] = wa;
    __syncthreads();
    for (int s = 64; s >= 1; s >>= 1) {
        if (b < s) red[b] += red[b + s];
        __syncthreads();
    }
    const double ww = red[0];
    const double alpha = d_alpha();

    double v = 0.0, Sb = 0.0;
#pragma unroll 8
    for (int t = 0; t < NT; ++t) {
        const double s = s64t[(long)t * NB + b];
        v = alpha * v + s;
        v_scr[(long)t * NB + b] = (float)v;
        z_scr[(long)t * NB + b] = (v - 2.0 > 0.0) ? 1.0f : 0.0f;
        Sb = fma(v, v, Sb);
        c_scr[(long)t * NB + b] = (float)(s - v * ww);
    }
    S_scr[b] = (float)Sb;

    double d = 0.0;
#pragma unroll 8
    for (int t = NT - 1; t >= 0; --t) {
        e_scr[(long)t * NB + b] = v_scr[(long)t * NB + b] + (float)d;  // e_t = v_t + d_t
        d = (double)c_scr[(long)t * NB + b] + alpha * d;               // d_{t-1} = c_t + alpha*d_t
    }
}

// ---------------------------------------------------------------------------
// passT: transpose v_scr/z_scr [T][B] -> v_out/z_out [B][T] via LDS tiles.
// grid (NB/16, NT/16), 256 threads, one element each.
// ---------------------------------------------------------------------------
__global__ __launch_bounds__(256) void passT_transpose(const float* __restrict__ v_scr,
                                                       const float* __restrict__ z_scr,
                                                       float* __restrict__ v_out,
                                                       float* __restrict__ z_out) {
    __shared__ float tv[16][17];
    __shared__ float tz[16][17];
    const int tb = blockIdx.x;       // b-tile: 0..7
    const int tt = blockIdx.y;       // t-tile: 0..124
    const int tx = threadIdx.x & 15;
    const int ty = threadIdx.x >> 4;
    const int t = tt * 16 + ty, b = tb * 16 + tx;
    tv[ty][tx] = v_scr[(long)t * NB + b];
    tz[ty][tx] = z_scr[(long)t * NB + b];
    __syncthreads();
    const int bo = tb * 16 + ty, to = tt * 16 + tx;
    v_out[(long)bo * NT + to] = tv[tx][ty];
    z_out[(long)bo * NT + to] = tz[tx][ty];
}

// ---------------------------------------------------------------------------
// passC: g_part[k,b,n] = sum_{t in chunk k} e[b,t] * x[b,t,n]
// block = (b,k), 512 threads: r = tid>>7 handles t = r mod 4; nq = tid&127 is n/4.
// ---------------------------------------------------------------------------
__global__ __launch_bounds__(512) void passC_wsum(const float* __restrict__ x,
                                                  const float* __restrict__ e_scr,
                                                  float* __restrict__ g_part) {
    __shared__ float e_lds[TC];
    __shared__ float4 red[512];
    const int b = blockIdx.x >> 3;   // / NK
    const int k = blockIdx.x & (NK - 1);
    const int tid = threadIdx.x;
    const int t0 = k * TC;
    if (tid < TC) e_lds[tid] = e_scr[(long)(t0 + tid) * NB + b];
    __syncthreads();
    const int r = tid >> 7;
    const int nq = tid & 127;
    const float4* xp = (const float4*)(x + ((long)(b * NT + t0)) * NN) + nq;
    float4 acc = make_float4(0.f, 0.f, 0.f, 0.f);
#pragma unroll 4
    for (int t = r; t < TC; t += 4) {
        const float ev = e_lds[t];
        const float4 xv = xp[(long)t * (NN / 4)];
        acc.x = fmaf(ev, xv.x, acc.x);
        acc.y = fmaf(ev, xv.y, acc.y);
        acc.z = fmaf(ev, xv.z, acc.z);
        acc.w = fmaf(ev, xv.w, acc.w);
    }
    red[tid] = acc;
    __syncthreads();
    if (tid < 128) {
        const float4 p0 = red[tid];
        const float4 p1 = red[tid + 128];
        const float4 p2 = red[tid + 256];
        const float4 p3 = red[tid + 384];
        float4 s;
        s.x = (p0.x + p1.x) + (p2.x + p3.x);
        s.y = (p0.y + p1.y) + (p2.y + p3.y);
        s.z = (p0.z + p1.z) + (p2.z + p3.z);
        s.w = (p0.w + p1.w) + (p2.w + p3.w);
        ((float4*)(g_part + ((long)k * NB + b) * NN))[tid] = s;
    }
}

// ---------------------------------------------------------------------------
// passD: g[b,n] = sum_k g_part[k,b,n] - S[b]*w[n]
// ---------------------------------------------------------------------------
__global__ __launch_bounds__(256) void passD_final(const float* __restrict__ g_part,
                                                   const float* __restrict__ S_scr,
                                                   const float* __restrict__ w,
                                                   float* __restrict__ g_out) {
    const int idx = blockIdx.x * 256 + threadIdx.x;  // idx = b*NN + n
    const int b = idx >> 9;
    const int n = idx & (NN - 1);
    float acc = 0.f;
#pragma unroll
    for (int kk = 0; kk < NK; ++kk) acc += g_part[((long)kk * NB + b) * NN + n];
    g_out[idx] = fmaf(-S_scr[b], w[n], acc);
}

// ---------------------------------------------------------------------------
extern "C" void kernel_launch(void* const* d_in, const int* in_sizes, int n_in,
                              void* d_out, int out_size, void* d_ws, size_t ws_size,
                              hipStream_t stream) {
    const float* x = (const float*)d_in[0];
    const float* w = (const float*)d_in[1];
    float* out = (float*)d_out;
    float* v_out = out;                       // [B,T]
    float* z_out = out + (long)NB * NT;       // [B,T]
    float* g_out = out + (long)2 * NB * NT;   // [B,N]

    char* ws = (char*)d_ws;
    double* s64t = (double*)(ws + 0);           // 2000*128*8 = 2,048,000 B
    float* v_scr = (float*)(ws + 2048000);      // 1,024,000 B  [t][b]
    float* z_scr = (float*)(ws + 3072000);      // 1,024,000 B  [t][b]
    float* c_scr = (float*)(ws + 4096000);      // 1,024,000 B  [t][b]
    float* e_scr = (float*)(ws + 5120000);      // 1,024,000 B  [t][b]
    float* S_scr = (float*)(ws + 6144000);      // 512 B
    float* g_prt = (float*)(ws + 6144512);      // 8*128*512*4 = 2,097,152 B (total ~8.3 MB)

    passA_dot<<<dim3(NB * NT / 4), dim3(256), 0, stream>>>(x, w, s64t);
    passB_scan<<<dim3(1), dim3(128), 0, stream>>>(s64t, w, v_scr, z_scr, c_scr, e_scr, S_scr);
    passT_transpose<<<dim3(NB / 16, NT / 16), dim3(256), 0, stream>>>(v_scr, z_scr, v_out, z_out);
    passC_wsum<<<dim3(NB * NK), dim3(512), 0, stream>>>(x, e_scr, g_prt);
    passD_final<<<dim3((NB * NN) / 256), dim3(256), 0, stream>>>(g_prt, S_scr, w, g_out);
}